// Round 1
// baseline (14.212 us; speedup 1.0000x reference)
//
#include <hip/hip_runtime.h>

#define NQ 4096
#define NM 32768
#define DF 8
#define TABLE_ENTRIES 65536  // 4^8 possible keys, 2 bits per feature

// Encode an 8-feature row (floats exactly representing ints 0..3) into a
// 16-bit code. Two float4 loads = 32B per row, fully coalesced.
__device__ __forceinline__ int encode_row(const float* __restrict__ row) {
    const float4* p = reinterpret_cast<const float4*>(row);
    float4 a = p[0];
    float4 c = p[1];
    return  ((int)a.x)       | (((int)a.y) << 2)  | (((int)a.z) << 4)  | (((int)a.w) << 6)
          | (((int)c.x) << 8) | (((int)c.y) << 10) | (((int)c.z) << 12) | (((int)c.w) << 14);
}

__global__ void build_table_kernel(const float* __restrict__ mem_keys,
                                   int* __restrict__ table) {
    int m = blockIdx.x * blockDim.x + threadIdx.x;
    if (m >= NM) return;
    int code = encode_row(mem_keys + m * DF);
    // Last duplicate wins (Python dict overwrite) == max index. atomicMax is
    // order-independent -> deterministic across replays.
    atomicMax(&table[code], m);
}

__global__ void lookup_kernel(const float* __restrict__ x,
                              const float* __restrict__ mem_values,
                              const float* __restrict__ w,
                              const float* __restrict__ bias,
                              const int* __restrict__ table,
                              float* __restrict__ out) {
    int i = blockIdx.x * blockDim.x + threadIdx.x;
    if (i >= NQ) return;
    const float4* p = reinterpret_cast<const float4*>(x + i * DF);
    float4 a = p[0];
    float4 c = p[1];
    int code = ((int)a.x)        | (((int)a.y) << 2)  | (((int)a.z) << 4)  | (((int)a.w) << 6)
             | (((int)c.x) << 8) | (((int)c.y) << 10) | (((int)c.z) << 12) | (((int)c.w) << 14);
    int idx = table[code];
    float r;
    if (idx >= 0) {
        r = mem_values[idx];
    } else {
        r = bias[0]
          + a.x * w[0] + a.y * w[1] + a.z * w[2] + a.w * w[3]
          + c.x * w[4] + c.y * w[5] + c.z * w[6] + c.w * w[7];
    }
    out[i] = r;
}

extern "C" void kernel_launch(void* const* d_in, const int* in_sizes, int n_in,
                              void* d_out, int out_size, void* d_ws, size_t ws_size,
                              hipStream_t stream) {
    const float* x          = (const float*)d_in[0];  // [4096, 8]
    const float* mem_keys   = (const float*)d_in[1];  // [32768, 8]
    const float* mem_values = (const float*)d_in[2];  // [32768]
    const float* w          = (const float*)d_in[3];  // [1, 8]
    const float* bias       = (const float*)d_in[4];  // [1]
    float* out              = (float*)d_out;          // [4096, 1]

    int* table = (int*)d_ws;  // 65536 ints = 256 KB

    // Init every slot to -1 (0xFFFFFFFF). Must happen every call: the harness
    // does not re-poison d_ws between replays.
    hipMemsetAsync(table, 0xFF, TABLE_ENTRIES * sizeof(int), stream);

    build_table_kernel<<<(NM + 255) / 256, 256, 0, stream>>>(mem_keys, table);
    lookup_kernel<<<(NQ + 255) / 256, 256, 0, stream>>>(x, mem_values, w, bias, table, out);
}